// Round 12
// baseline (1159.000 us; speedup 1.0000x reference)
//
#include <hip/hip_runtime.h>
#include <math.h>

#define BB 128
#define TT 512
#define HH 128
#define G4 512      // 4*H
#define CC 128
#define WW 32
#define TCHUNK 128  // time chunk for k1b/k1c ping-pong (4 chunks)

// ---- workspace layout (float slots) ----
#define OFF_FCWT  0                          // 16384
#define OFF_W1P   (OFF_FCWT + CC*HH)         // f16 permuted Whh1: 32768 slots
#define OFF_WI2P  (OFF_W1P  + G4*HH/2)
#define OFF_WH2P  (OFF_WI2P + G4*HH/2)
#define OFF_B1P   (OFF_WH2P + G4*HH/2)       // 512
#define OFF_WI1P  (OFF_B1P + G4)
#define OFF_B2P   (OFF_WI1P + G4)
#define OFF_H2A   (OFF_B2P + G4)             // [T][B][H] fp32
#define OFF_DOLD  (OFF_H2A + TT*BB*HH)
#define OFF_DH    (OFF_DOLD + TT*BB)
#define OFF_MT    (OFF_DH + TT*BB)
#define OFF_ST    (OFF_MT + TT)
#define OFF_C1F   (OFF_ST + TT)              // f16 [t][b][h]: TT*BB*HH/2 slots
#define OFF_C2S   (OFF_C1F + TT*BB*HH/2)     // f32 [b][h] c2 checkpoint
#define OFF_GI2   (OFF_C2S + BB*HH)          // f32 [b][tc][r]: TCHUNK*BB*G4
// top ~= 21.2M floats ~= 85 MB

typedef _Float16 h2t __attribute__((ext_vector_type(2)));

__device__ __forceinline__ unsigned short f16b(float v) {
    return __builtin_bit_cast(unsigned short, (_Float16)v);
}
__device__ __forceinline__ float dot2f(unsigned int a, unsigned int b, float acc) {
#if defined(__has_builtin) && __has_builtin(__builtin_amdgcn_fdot2)
    return __builtin_amdgcn_fdot2(__builtin_bit_cast(h2t, a),
                                  __builtin_bit_cast(h2t, b), acc, false);
#else
    h2t av = __builtin_bit_cast(h2t, a), bv = __builtin_bit_cast(h2t, b);
    acc = fmaf((float)av.x, (float)bv.x, acc);
    acc = fmaf((float)av.y, (float)bv.y, acc);
    return acc;
#endif
}
__device__ __forceinline__ float rcpf(float x) {
#if defined(__has_builtin) && __has_builtin(__builtin_amdgcn_rcpf)
    return __builtin_amdgcn_rcpf(x);
#else
    return 1.f / x;
#endif
}
__device__ __forceinline__ float sigf(float v) {
    return rcpf(1.f + __expf(-v));
}
__device__ __forceinline__ float tanhf_(float v) {
    return fmaf(2.f, rcpf(1.f + __expf(-2.f * v)), -1.f);
}

// DPP quad_perm helpers (pure VALU, quad-local).
template <int CTRL>
__device__ __forceinline__ float dppadd(float v) {
#if defined(__has_builtin) && __has_builtin(__builtin_amdgcn_update_dpp)
    int m = __builtin_amdgcn_update_dpp(0, __builtin_bit_cast(int, v),
                                        CTRL, 0xf, 0xf, true);
    return v + __builtin_bit_cast(float, m);
#else
    return v + __shfl_xor(v, CTRL == 0xB1 ? 1 : 2);
#endif
}

// 32 dot2: one 64-col row-slice (8 uint4 f16 weights) x state (8 uint4)
__device__ __forceinline__ void dot32(float& acc, const uint4* W, const uint4* S) {
    #pragma unroll
    for (int k = 0; k < 8; ++k) {
        acc = dot2f(W[k].x, S[k].x, acc);
        acc = dot2f(W[k].y, S[k].y, acc);
        acc = dot2f(W[k].z, S[k].z, acc);
        acc = dot2f(W[k].w, S[k].w, acc);
    }
}
// 8 dot2: one 16-col row-slice (2 uint4 f16 weights) x state (2 uint4)
__device__ __forceinline__ float dot16(const uint4* W, uint4 s0, uint4 s1) {
    float acc = 0.f;
    acc = dot2f(W[0].x, s0.x, acc); acc = dot2f(W[0].y, s0.y, acc);
    acc = dot2f(W[0].z, s0.z, acc); acc = dot2f(W[0].w, s0.w, acc);
    acc = dot2f(W[1].x, s1.x, acc); acc = dot2f(W[1].y, s1.y, acc);
    acc = dot2f(W[1].z, s1.z, acc); acc = dot2f(W[1].w, s1.w, acc);
    return acc;
}

// LDS-visibility barrier WITHOUT vmcnt drain.
#define STEP_BARRIER() asm volatile("s_waitcnt lgkmcnt(0)\n\ts_barrier" ::: "memory")

// K0: gate-interleaved (r = h*4 + g) f16 weight images + permuted biases +
// fcW transpose.  (unchanged)
__global__ __launch_bounds__(256) void k0_prep(
    const float* __restrict__ Whh1, const float* __restrict__ Wih2,
    const float* __restrict__ Whh2, const float* __restrict__ fcW,
    const float* __restrict__ Wih1,
    const float* __restrict__ bih1, const float* __restrict__ bhh1,
    const float* __restrict__ bih2, const float* __restrict__ bhh2,
    float* __restrict__ fcWT,
    unsigned short* __restrict__ w1p, unsigned short* __restrict__ wi2p,
    unsigned short* __restrict__ wh2p,
    float* __restrict__ b1p, float* __restrict__ wi1p, float* __restrict__ b2p)
{
    int idx = blockIdx.x * blockDim.x + threadIdx.x;
    if (idx < G4 * HH) {
        int r_old = idx >> 7, k = idx & 127;
        int g = r_old >> 7, h = r_old & 127;
        int dst = (h * 4 + g) * HH + k;
        w1p [dst] = f16b(Whh1[idx]);
        wi2p[dst] = f16b(Wih2[idx]);
        wh2p[dst] = f16b(Whh2[idx]);
    }
    if (idx < CC * HH) {
        int c = idx / HH, h = idx % HH;
        fcWT[h * CC + c] = fcW[idx];
    }
    if (idx < G4) {
        int g = idx >> 7, h = idx & 127;
        int rn = h * 4 + g;
        b1p [rn] = bih1[idx] + bhh1[idx];
        wi1p[rn] = Wih1[idx];
        b2p [rn] = bih2[idx] + bhh2[idx];
    }
}

// K1a: LAYER-1 recurrence, latency-optimized.  1024 threads; thread =
// (unit h = tid>>3, 16-col slice s = tid&7).  Per thread: ALL 4 gate rows x
// 16 cols = 32 weight dwords (total regs ~80 -> 4 waves/SIMD at
// waves_per_eu(4,4), double R11's occupancy; dot chains halve to 8-deep).
// Reduce: xor1+xor2 in-quad DPP + ONE parallel shfl_xor(4) layer; cell math
// then fully lane-local (no cross-lane combine on the critical path).
__global__ __launch_bounds__(1024)
__attribute__((amdgpu_waves_per_eu(4, 4)))
void k1a_lstm1(
    const float* __restrict__ x,
    const float* __restrict__ b1p, const float* __restrict__ wi1p,
    const unsigned short* __restrict__ w1p,
    unsigned short* __restrict__ c1f)
{
    __shared__ __align__(16) unsigned short h1h[2][HH];
    __shared__ float xs[TT];

    const int tid = threadIdx.x;
    const int b   = blockIdx.x;
    const int s   = tid & 7;             // col slice [16s, 16s+16)
    const int h   = tid >> 3;            // unit 0..127

    uint4 w1[4][2];                      // 4 rows x 16 cols = 32 dwords
    float wi1v[4], b1v[4];
    #pragma unroll
    for (int r = 0; r < 4; ++r) {
        const uint4* p1 = (const uint4*)(w1p + (size_t)(4 * h + r) * HH + 16 * s);
        w1[r][0] = p1[0]; w1[r][1] = p1[1];
        wi1v[r] = wi1p[4 * h + r];
        b1v[r]  = b1p [4 * h + r];
    }

    if (tid < TT) xs[tid] = x[(size_t)b * TT + tid];
    if (tid < HH) { h1h[0][tid] = 0; h1h[1][tid] = 0; }
    float c1reg = 0.f;                   // replicated across the 8 lanes
    __syncthreads();

    unsigned short* outc = c1f + (size_t)b * HH + h;   // [t][b][h]

    for (int u = 0; u < TT; ++u) {
        const int p = u & 1, q = p ^ 1;
        const float xv = xs[u];

        const uint4* hp = (const uint4*)&h1h[p][16 * s];
        uint4 s0 = hp[0], s1 = hp[1];
        float a0 = dot16(w1[0], s0, s1);
        float a1 = dot16(w1[1], s0, s1);
        float a2 = dot16(w1[2], s0, s1);
        float a3 = dot16(w1[3], s0, s1);
        // in-quad reduce (cols within 64-col half)
        a0 = dppadd<0xB1>(a0); a0 = dppadd<0x4E>(a0);
        a1 = dppadd<0xB1>(a1); a1 = dppadd<0x4E>(a1);
        a2 = dppadd<0xB1>(a2); a2 = dppadd<0x4E>(a2);
        a3 = dppadd<0xB1>(a3); a3 = dppadd<0x4E>(a3);
        // cross-quad (other 64-col half): 4 independent swizzles, one hop
        a0 += __shfl_xor(a0, 4);
        a1 += __shfl_xor(a1, 4);
        a2 += __shfl_xor(a2, 4);
        a3 += __shfl_xor(a3, 4);

        float gi = a0 + fmaf(xv, wi1v[0], b1v[0]);
        float gf = a1 + fmaf(xv, wi1v[1], b1v[1]);
        float gg = a2 + fmaf(xv, wi1v[2], b1v[2]);
        float go = a3 + fmaf(xv, wi1v[3], b1v[3]);
        float cn = sigf(gf) * c1reg + sigf(gi) * tanhf_(gg);
        c1reg = cn;
        float hn = sigf(go) * tanhf_(cn);
        if (s == 0) {
            h1h[q][h] = f16b(hn);
            outc[(size_t)u * (BB * HH)] = f16b(cn);
        }
        STEP_BARRIER();
    }
}

// K1b: chunked batch GEMM gi2[b][tc][r] = f32( b2[r] + Wih2[r,:].c1[t0+tc,b,:] ).
// (R11-proven full-K slice+DPP-reduce structure -- unchanged.)
__global__ __launch_bounds__(512) void k1b_gemm(
    const unsigned short* __restrict__ c1f,
    const unsigned short* __restrict__ wi2p,
    const float* __restrict__ b2p,
    float* __restrict__ gi2, int t0)
{
    const int tl0 = blockIdx.x * 16;
    const int b   = blockIdx.y;
    const int tid = threadIdx.x;
    const int rq  = tid >> 1;            // row pair 0..255 -> rows 2rq, 2rq+1
    const int s   = tid & 1;             // col half

    __shared__ __align__(16) unsigned short c1t[16][HH];   // 4 KB
    {
        int row = tid >> 5;              // 0..15
        int col = (tid & 31) * 4;        // 0..124 halfwords
        *(uint2*)&c1t[row][col] =
            *(const uint2*)(c1f + ((size_t)(t0 + tl0 + row) * BB + b) * HH + col);
    }
    uint4 wa[8], wb[8];                  // rows 2rq, 2rq+1, col half s
    {
        const uint4* pa = (const uint4*)(wi2p + (size_t)(2 * rq) * HH + 64 * s);
        const uint4* pb = (const uint4*)(wi2p + (size_t)(2 * rq + 1) * HH + 64 * s);
        #pragma unroll
        for (int k = 0; k < 8; ++k) { wa[k] = pa[k]; wb[k] = pb[k]; }
    }
    const float bias = b2p[2 * rq + s];  // bias of the row THIS lane writes
    __syncthreads();

    float* gout = gi2 + ((size_t)b * TCHUNK + tl0) * G4;
    #pragma unroll 4
    for (int tt = 0; tt < 16; ++tt) {
        uint4 sv[8];
        const uint4* cp = (const uint4*)&c1t[tt][64 * s];
        #pragma unroll
        for (int k = 0; k < 8; ++k) sv[k] = cp[k];
        float d0 = 0.f, d1 = 0.f;
        dot32(d0, wa, sv);
        dot32(d1, wb, sv);
        float D0 = dppadd<0xB1>(d0);     // full-K sum, row 2rq
        float D1 = dppadd<0xB1>(d1);     // full-K sum, row 2rq+1
        float v  = (s ? D1 : D0) + bias;
        gout[(size_t)tt * G4 + 2 * rq + s] = v;
    }
}

// K1c: chunked LAYER-2 recurrence, latency-optimized like k1a (1024 threads,
// 8 lanes/unit, lane-local cell).  Wih2 contribution read precomputed as one
// aligned float4 (rows 4h..4h+3, gate-interleaved order) with rolling
// prefetch.  c2 checkpointed between chunks; h2(t0-1) reseeded from h2a f32
// (f32->f16 re-round is bit-identical to the in-loop f16 handoff).
__global__ __launch_bounds__(1024)
__attribute__((amdgpu_waves_per_eu(4, 4)))
void k1c_lstm2(
    const float* __restrict__ gi2,
    const unsigned short* __restrict__ wh2p,
    float* __restrict__ h2a, float* __restrict__ c2s, int t0)
{
    __shared__ __align__(16) unsigned short h2h[2][HH];

    const int tid = threadIdx.x;
    const int b   = blockIdx.x;
    const int s   = tid & 7;             // col slice [16s, 16s+16)
    const int h   = tid >> 3;            // unit 0..127

    uint4 w2[4][2];                      // 4 rows x 16 cols = 32 dwords
    #pragma unroll
    for (int r = 0; r < 4; ++r) {
        const uint4* p1 = (const uint4*)(wh2p + (size_t)(4 * h + r) * HH + 16 * s);
        w2[r][0] = p1[0]; w2[r][1] = p1[1];
    }

    if (tid < HH) {
        unsigned short hv = 0;
        if (t0 > 0) hv = f16b(h2a[((size_t)(t0 - 1) * BB + b) * HH + tid]);
        h2h[0][tid] = hv;
        h2h[1][tid] = 0;
    }
    float c2reg = (t0 > 0) ? c2s[b * HH + h] : 0.f;   // replicated
    __syncthreads();

    const float* gbase = gi2 + (size_t)b * TCHUNK * G4 + 4 * h;
    float* outp = h2a + (size_t)b * HH + h;

    float4 gc = *(const float4*)gbase;   // tc=0: rows 4h..4h+3 (i,f,g,o)
    for (int ts = 0; ts < TCHUNK; ++ts) {
        const int p = ts & 1, q = p ^ 1;

        float4 gn = make_float4(0.f, 0.f, 0.f, 0.f);
        if (ts + 1 < TCHUNK) gn = *(const float4*)(gbase + (size_t)(ts + 1) * G4);

        const uint4* hp = (const uint4*)&h2h[p][16 * s];
        uint4 s0 = hp[0], s1 = hp[1];
        float a0 = dot16(w2[0], s0, s1);
        float a1 = dot16(w2[1], s0, s1);
        float a2 = dot16(w2[2], s0, s1);
        float a3 = dot16(w2[3], s0, s1);
        a0 = dppadd<0xB1>(a0); a0 = dppadd<0x4E>(a0);
        a1 = dppadd<0xB1>(a1); a1 = dppadd<0x4E>(a1);
        a2 = dppadd<0xB1>(a2); a2 = dppadd<0x4E>(a2);
        a3 = dppadd<0xB1>(a3); a3 = dppadd<0x4E>(a3);
        a0 += __shfl_xor(a0, 4);
        a1 += __shfl_xor(a1, 4);
        a2 += __shfl_xor(a2, 4);
        a3 += __shfl_xor(a3, 4);

        float gi = a0 + gc.x;
        float gf = a1 + gc.y;
        float gg = a2 + gc.z;
        float go = a3 + gc.w;
        float cn = sigf(gf) * c2reg + sigf(gi) * tanhf_(gg);
        c2reg = cn;
        float hn = sigf(go) * tanhf_(cn);
        if (s == 0) {
            h2h[q][h] = f16b(hn);
            outp[(size_t)(t0 + ts) * (BB * HH)] = hn;
        }
        gc = gn;
        STEP_BARRIER();
    }
    if (s == 0) c2s[b * HH + h] = c2reg;   // checkpoint for next chunk
}

// K2: d_old[t,b] = h2[t,b,:].wt_old ; d_h[t,b] = h2[t,b,:].wt_h  (unchanged)
__global__ __launch_bounds__(256) void k2_dots(
    const float* __restrict__ h2a, const float* __restrict__ w_t,
    float* __restrict__ dold, float* __restrict__ dh)
{
    const int lane = threadIdx.x & 63;
    const int wave = blockIdx.x * (blockDim.x >> 6) + (threadIdx.x >> 6);
    const int nw = gridDim.x * (blockDim.x >> 6);
    const float wh0 = w_t[lane],       wh1 = w_t[64 + lane];
    const float wo0 = w_t[128 + lane], wo1 = w_t[192 + lane];
    for (int row = wave; row < TT * BB; row += nw) {
        const float* p = h2a + (size_t)row * HH;
        float v0 = p[lane], v1 = p[64 + lane];
        float po = v0 * wo0 + v1 * wo1;
        float ph = v0 * wh0 + v1 * wh1;
        #pragma unroll
        for (int off = 32; off; off >>= 1) {
            po += __shfl_xor(po, off);
            ph += __shfl_xor(ph, off);
        }
        if (lane == 0) { dold[row] = po; dh[row] = ph; }
    }
}

// K3: per-t global softmax stats over valid (j,b): m[t], s[t]  (unchanged)
__global__ __launch_bounds__(256) void k3_stats(
    const float* __restrict__ dold, const float* __restrict__ dh,
    float* __restrict__ mt, float* __restrict__ st)
{
    const int t = blockIdx.x;
    const int tid = threadIdx.x;
    const int cnt = (min(t, WW) + 1) * BB;
    const int jstart = max(t - (WW + 1), -1);

    float m = -INFINITY;
    for (int idx = tid; idx < cnt; idx += 256) {
        int jj = idx >> 7, b = idx & 127;
        int j = jstart + jj;
        float sc = dh[t * BB + b] + (j >= 0 ? dold[j * BB + b] : 0.f);
        m = fmaxf(m, sc);
    }
    #pragma unroll
    for (int off = 32; off; off >>= 1) m = fmaxf(m, __shfl_xor(m, off));
    __shared__ float rbuf[4];
    int wv = tid >> 6, ln = tid & 63;
    if (ln == 0) rbuf[wv] = m;
    __syncthreads();
    m = fmaxf(fmaxf(rbuf[0], rbuf[1]), fmaxf(rbuf[2], rbuf[3]));

    float s = 0.f;
    for (int idx = tid; idx < cnt; idx += 256) {
        int jj = idx >> 7, b = idx & 127;
        int j = jstart + jj;
        float sc = dh[t * BB + b] + (j >= 0 ? dold[j * BB + b] : 0.f);
        s += __expf(sc - m);
    }
    #pragma unroll
    for (int off = 32; off; off >>= 1) s += __shfl_xor(s, off);
    __shared__ float sbuf[4];
    if (ln == 0) sbuf[wv] = s;
    __syncthreads();
    if (tid == 0) { mt[t] = m; st[t] = sbuf[0] + sbuf[1] + sbuf[2] + sbuf[3]; }
}

// K45: fused attention + FC. grid (TT/8, BB), block 256.  (unchanged)
__global__ __launch_bounds__(256) void k45_attn_fc(
    const float* __restrict__ h2a,
    const float* __restrict__ dold, const float* __restrict__ dh,
    const float* __restrict__ mt, const float* __restrict__ st,
    const float* __restrict__ fcWT, const float* __restrict__ fcb,
    float* __restrict__ out)
{
    const int t0 = blockIdx.x * 8;
    const int b  = blockIdx.y;
    const int tid = threadIdx.x;

    __shared__ float hbuf[41][HH];     // rows t0-33 .. t0+7
    __shared__ float wjs[8][36];
    __shared__ float ytile[8][HH];

    for (int i = tid; i < 41 * 32; i += 256) {
        int r = i >> 5, q4 = i & 31;
        int t = t0 - 33 + r;
        float4 v = make_float4(0.f, 0.f, 0.f, 0.f);
        if (t >= 0)
            v = *(const float4*)(h2a + (size_t)t * (BB * HH) + (size_t)b * HH + q4 * 4);
        *(float4*)&hbuf[r][q4 * 4] = v;
    }
    for (int i = tid; i < 8 * 33; i += 256) {
        int tt = i / 33, ss = i % 33;
        int t = t0 + tt, j = t - 33 + ss;
        float w = 0.f;
        if (j >= 0)
            w = __expf(dold[j * BB + b] + dh[t * BB + b] - mt[t]) / st[t];
        wjs[tt][ss] = w;
    }
    __syncthreads();

    {
        const int tq = tid >> 5;
        const int hq = (tid & 31) * 4;
        float4 acc = *(const float4*)&hbuf[tq + 33][hq];   // h2[t]
        #pragma unroll 11
        for (int ss = 0; ss < 33; ++ss) {
            float w = wjs[tq][ss];
            float4 hb = *(const float4*)&hbuf[tq + ss][hq];
            acc.x = fmaf(w, hb.x, acc.x);
            acc.y = fmaf(w, hb.y, acc.y);
            acc.z = fmaf(w, hb.z, acc.z);
            acc.w = fmaf(w, hb.w, acc.w);
        }
        *(float4*)&ytile[tq][hq] = acc;
    }
    __syncthreads();

    {
        const int c  = tid & 127;
        const int th = tid >> 7;
        float acc[4];
        const float bias = fcb[c];
        #pragma unroll
        for (int i = 0; i < 4; ++i) acc[i] = bias;
        for (int hh = 0; hh < HH; ++hh) {
            float w = fcWT[hh * CC + c];
            #pragma unroll
            for (int i = 0; i < 4; ++i)
                acc[i] = fmaf(ytile[th * 4 + i][hh], w, acc[i]);
        }
        #pragma unroll
        for (int i = 0; i < 4; ++i) {
            int t = t0 + th * 4 + i;
            out[(size_t)b * (TT * CC) + (size_t)t * CC + c] = acc[i];
        }
    }
}

extern "C" void kernel_launch(void* const* d_in, const int* in_sizes, int n_in,
                              void* d_out, int out_size, void* d_ws, size_t ws_size,
                              hipStream_t stream)
{
    const float* x    = (const float*)d_in[0];
    const float* Wih1 = (const float*)d_in[1];
    const float* Whh1 = (const float*)d_in[2];
    const float* bih1 = (const float*)d_in[3];
    const float* bhh1 = (const float*)d_in[4];
    const float* Wih2 = (const float*)d_in[5];
    const float* Whh2 = (const float*)d_in[6];
    const float* bih2 = (const float*)d_in[7];
    const float* bhh2 = (const float*)d_in[8];
    const float* w_t  = (const float*)d_in[9];
    const float* fcW  = (const float*)d_in[10];
    const float* fcb  = (const float*)d_in[11];
    float* out = (float*)d_out;

    float* ws   = (float*)d_ws;
    float* fcWT = ws + OFF_FCWT;
    unsigned short* w1p  = (unsigned short*)(ws + OFF_W1P);
    unsigned short* wi2p = (unsigned short*)(ws + OFF_WI2P);
    unsigned short* wh2p = (unsigned short*)(ws + OFF_WH2P);
    float* b1pp = ws + OFF_B1P;
    float* wi1p = ws + OFF_WI1P;
    float* b2pp = ws + OFF_B2P;
    float* h2a  = ws + OFF_H2A;
    float* dold = ws + OFF_DOLD;
    float* dh   = ws + OFF_DH;
    float* mt   = ws + OFF_MT;
    float* st   = ws + OFF_ST;
    unsigned short* c1f = (unsigned short*)(ws + OFF_C1F);
    float* c2s  = ws + OFF_C2S;
    float* gi2  = ws + OFF_GI2;

    k0_prep<<<dim3((G4 * HH + 255) / 256), dim3(256), 0, stream>>>(
        Whh1, Wih2, Whh2, fcW, Wih1, bih1, bhh1, bih2, bhh2,
        fcWT, w1p, wi2p, wh2p, b1pp, wi1p, b2pp);

    k1a_lstm1<<<dim3(BB), dim3(1024), 0, stream>>>(
        x, b1pp, wi1p, w1p, c1f);

    for (int t0 = 0; t0 < TT; t0 += TCHUNK) {
        k1b_gemm<<<dim3(TCHUNK / 16, BB), dim3(512), 0, stream>>>(
            c1f, wi2p, b2pp, gi2, t0);
        k1c_lstm2<<<dim3(BB), dim3(1024), 0, stream>>>(
            gi2, wh2p, h2a, c2s, t0);
    }

    k2_dots<<<dim3(256), dim3(256), 0, stream>>>(h2a, w_t, dold, dh);

    k3_stats<<<dim3(TT), dim3(256), 0, stream>>>(dold, dh, mt, st);

    k45_attn_fc<<<dim3(TT / 8, BB), dim3(256), 0, stream>>>(
        h2a, dold, dh, mt, st, fcWT, fcb, out);
}

// Round 13
// 892.406 us; speedup vs baseline: 1.2987x; 1.2987x over previous
//
#include <hip/hip_runtime.h>
#include <math.h>

#define BB 128
#define TT 512
#define HH 128
#define G4 512      // 4*H
#define CC 128
#define WW 32
#define TCHUNK 128  // time chunk for k1b/k1c ping-pong (4 chunks)

// ---- workspace layout (float slots) ----
#define OFF_FCWT  0                          // 16384
#define OFF_W1P   (OFF_FCWT + CC*HH)         // f16 permuted Whh1: 32768 slots
#define OFF_WI2P  (OFF_W1P  + G4*HH/2)
#define OFF_WH2P  (OFF_WI2P + G4*HH/2)
#define OFF_B1P   (OFF_WH2P + G4*HH/2)       // 512
#define OFF_WI1P  (OFF_B1P + G4)
#define OFF_B2P   (OFF_WI1P + G4)
#define OFF_H2A   (OFF_B2P + G4)             // [T][B][H] fp32
#define OFF_DOLD  (OFF_H2A + TT*BB*HH)
#define OFF_DH    (OFF_DOLD + TT*BB)
#define OFF_MT    (OFF_DH + TT*BB)
#define OFF_ST    (OFF_MT + TT)
#define OFF_C1F   (OFF_ST + TT)              // f16 [t][b][h]: TT*BB*HH/2 slots
#define OFF_C2S   (OFF_C1F + TT*BB*HH/2)     // f32 [b][h] c2 checkpoint
#define OFF_GI2   (OFF_C2S + BB*HH)          // f32 [b][tc][r]: TCHUNK*BB*G4
// top ~= 21.2M floats ~= 85 MB

typedef _Float16 h2t __attribute__((ext_vector_type(2)));

__device__ __forceinline__ unsigned short f16b(float v) {
    return __builtin_bit_cast(unsigned short, (_Float16)v);
}
__device__ __forceinline__ float dot2f(unsigned int a, unsigned int b, float acc) {
#if defined(__has_builtin) && __has_builtin(__builtin_amdgcn_fdot2)
    return __builtin_amdgcn_fdot2(__builtin_bit_cast(h2t, a),
                                  __builtin_bit_cast(h2t, b), acc, false);
#else
    h2t av = __builtin_bit_cast(h2t, a), bv = __builtin_bit_cast(h2t, b);
    acc = fmaf((float)av.x, (float)bv.x, acc);
    acc = fmaf((float)av.y, (float)bv.y, acc);
    return acc;
#endif
}
__device__ __forceinline__ float rcpf(float x) {
#if defined(__has_builtin) && __has_builtin(__builtin_amdgcn_rcpf)
    return __builtin_amdgcn_rcpf(x);
#else
    return 1.f / x;
#endif
}
__device__ __forceinline__ float sigf(float v) {
    return rcpf(1.f + __expf(-v));
}
__device__ __forceinline__ float tanhf_(float v) {
    return fmaf(2.f, rcpf(1.f + __expf(-2.f * v)), -1.f);
}

// DPP quad_perm helpers (pure VALU, quad-local).
template <int CTRL>
__device__ __forceinline__ float dppadd(float v) {
#if defined(__has_builtin) && __has_builtin(__builtin_amdgcn_update_dpp)
    int m = __builtin_amdgcn_update_dpp(0, __builtin_bit_cast(int, v),
                                        CTRL, 0xf, 0xf, true);
    return v + __builtin_bit_cast(float, m);
#else
    return v + __shfl_xor(v, CTRL == 0xB1 ? 1 : 2);
#endif
}
// full quad sum: xor1 + xor2 (both quad_perm DPP, never DS-pipe)
__device__ __forceinline__ float qsum(float v) {
    v = dppadd<0xB1>(v);
    v = dppadd<0x4E>(v);
    return v;
}

// 32 dot2: one 64-col row-slice (8 uint4 f16 weights) x state (8 uint4)
__device__ __forceinline__ void dot32(float& acc, const uint4* W, const uint4* S) {
    #pragma unroll
    for (int k = 0; k < 8; ++k) {
        acc = dot2f(W[k].x, S[k].x, acc);
        acc = dot2f(W[k].y, S[k].y, acc);
        acc = dot2f(W[k].z, S[k].z, acc);
        acc = dot2f(W[k].w, S[k].w, acc);
    }
}
// 16 dot2: one 32-col row-slice (4 uint4 f16 weights) x state (4 uint4)
__device__ __forceinline__ float dotrow32(const uint4* W, const uint4* S) {
    float acc = 0.f;
    #pragma unroll
    for (int k = 0; k < 4; ++k) {
        acc = dot2f(W[k].x, S[k].x, acc);
        acc = dot2f(W[k].y, S[k].y, acc);
        acc = dot2f(W[k].z, S[k].z, acc);
        acc = dot2f(W[k].w, S[k].w, acc);
    }
    return acc;
}

// LDS-visibility barrier WITHOUT vmcnt drain.
#define STEP_BARRIER() asm volatile("s_waitcnt lgkmcnt(0)\n\ts_barrier" ::: "memory")

// K0: gate-interleaved (r = h*4 + g) f16 weight images + permuted biases +
// fcW transpose.  (unchanged)
__global__ __launch_bounds__(256) void k0_prep(
    const float* __restrict__ Whh1, const float* __restrict__ Wih2,
    const float* __restrict__ Whh2, const float* __restrict__ fcW,
    const float* __restrict__ Wih1,
    const float* __restrict__ bih1, const float* __restrict__ bhh1,
    const float* __restrict__ bih2, const float* __restrict__ bhh2,
    float* __restrict__ fcWT,
    unsigned short* __restrict__ w1p, unsigned short* __restrict__ wi2p,
    unsigned short* __restrict__ wh2p,
    float* __restrict__ b1p, float* __restrict__ wi1p, float* __restrict__ b2p)
{
    int idx = blockIdx.x * blockDim.x + threadIdx.x;
    if (idx < G4 * HH) {
        int r_old = idx >> 7, k = idx & 127;
        int g = r_old >> 7, h = r_old & 127;
        int dst = (h * 4 + g) * HH + k;
        w1p [dst] = f16b(Whh1[idx]);
        wi2p[dst] = f16b(Wih2[idx]);
        wh2p[dst] = f16b(Whh2[idx]);
    }
    if (idx < CC * HH) {
        int c = idx / HH, h = idx % HH;
        fcWT[h * CC + c] = fcW[idx];
    }
    if (idx < G4) {
        int g = idx >> 7, h = idx & 127;
        int rn = h * 4 + g;
        b1p [rn] = bih1[idx] + bhh1[idx];
        wi1p[rn] = Wih1[idx];
        b2p [rn] = bih2[idx] + bhh2[idx];
    }
}

// K1a: LAYER-1 recurrence.  512 threads; thread = (unit h = tid>>2, 32-col
// slice s = tid&3), owning ALL 4 gate rows x 32 cols = 64 weight dwords (the
// register-resident size proven in R11).  vs R11: DS reads halve (4
// ds_read_b128/thread); vs R12: reduction is quad-only DPP (xor1+xor2, no
// ds_swizzle) and activation replication is 4x not 8x.  The per-CU DS pipe
// (the measured governor in R11/R12) drops to ~32 instr/step.
__global__ __launch_bounds__(512)
__attribute__((amdgpu_waves_per_eu(2, 2)))
void k1a_lstm1(
    const float* __restrict__ x,
    const float* __restrict__ b1p, const float* __restrict__ wi1p,
    const unsigned short* __restrict__ w1p,
    unsigned short* __restrict__ c1f)
{
    __shared__ __align__(16) unsigned short h1h[2][HH];
    __shared__ float xs[TT];

    const int tid = threadIdx.x;
    const int b   = blockIdx.x;
    const int s   = tid & 3;             // 32-col slice [32s, 32s+32)
    const int h   = tid >> 2;            // unit 0..127

    uint4 w1[4][4];                      // 4 rows x 32 cols = 64 dwords
    float wi1v[4], b1v[4];
    #pragma unroll
    for (int r = 0; r < 4; ++r) {
        const uint4* p1 = (const uint4*)(w1p + (size_t)(4 * h + r) * HH + 32 * s);
        #pragma unroll
        for (int k = 0; k < 4; ++k) w1[r][k] = p1[k];
        wi1v[r] = wi1p[4 * h + r];
        b1v[r]  = b1p [4 * h + r];
    }

    xs[tid] = x[(size_t)b * TT + tid];
    if (tid < HH) { h1h[0][tid] = 0; h1h[1][tid] = 0; }
    float c1reg = 0.f;                   // replicated across the 4 lanes
    __syncthreads();

    unsigned short* outc = c1f + (size_t)b * HH + h;   // [t][b][h]

    for (int u = 0; u < TT; ++u) {
        const int p = u & 1, q = p ^ 1;
        const float xv = xs[u];

        uint4 sv[4];
        const uint4* hp = (const uint4*)&h1h[p][32 * s];
        #pragma unroll
        for (int k = 0; k < 4; ++k) sv[k] = hp[k];
        float a0 = dotrow32(w1[0], sv);
        float a1 = dotrow32(w1[1], sv);
        float a2 = dotrow32(w1[2], sv);
        float a3 = dotrow32(w1[3], sv);
        // quad-only reduce: every lane gets full-K sums of all 4 gates
        a0 = qsum(a0); a1 = qsum(a1); a2 = qsum(a2); a3 = qsum(a3);

        float gi = a0 + fmaf(xv, wi1v[0], b1v[0]);
        float gf = a1 + fmaf(xv, wi1v[1], b1v[1]);
        float gg = a2 + fmaf(xv, wi1v[2], b1v[2]);
        float go = a3 + fmaf(xv, wi1v[3], b1v[3]);
        float cn = sigf(gf) * c1reg + sigf(gi) * tanhf_(gg);
        c1reg = cn;
        float hn = sigf(go) * tanhf_(cn);
        if (s == 0) {
            h1h[q][h] = f16b(hn);
            outc[(size_t)u * (BB * HH)] = f16b(cn);
        }
        STEP_BARRIER();
    }
}

// K1b: chunked batch GEMM gi2[b][tc][r] = f32( b2[r] + Wih2[r,:].c1[t0+tc,b,:] ).
// (R11-proven full-K slice+DPP-reduce structure -- unchanged.)
__global__ __launch_bounds__(512) void k1b_gemm(
    const unsigned short* __restrict__ c1f,
    const unsigned short* __restrict__ wi2p,
    const float* __restrict__ b2p,
    float* __restrict__ gi2, int t0)
{
    const int tl0 = blockIdx.x * 16;
    const int b   = blockIdx.y;
    const int tid = threadIdx.x;
    const int rq  = tid >> 1;            // row pair 0..255 -> rows 2rq, 2rq+1
    const int s   = tid & 1;             // col half

    __shared__ __align__(16) unsigned short c1t[16][HH];   // 4 KB
    {
        int row = tid >> 5;              // 0..15
        int col = (tid & 31) * 4;        // 0..124 halfwords
        *(uint2*)&c1t[row][col] =
            *(const uint2*)(c1f + ((size_t)(t0 + tl0 + row) * BB + b) * HH + col);
    }
    uint4 wa[8], wb[8];                  // rows 2rq, 2rq+1, col half s
    {
        const uint4* pa = (const uint4*)(wi2p + (size_t)(2 * rq) * HH + 64 * s);
        const uint4* pb = (const uint4*)(wi2p + (size_t)(2 * rq + 1) * HH + 64 * s);
        #pragma unroll
        for (int k = 0; k < 8; ++k) { wa[k] = pa[k]; wb[k] = pb[k]; }
    }
    const float bias = b2p[2 * rq + s];  // bias of the row THIS lane writes
    __syncthreads();

    float* gout = gi2 + ((size_t)b * TCHUNK + tl0) * G4;
    #pragma unroll 4
    for (int tt = 0; tt < 16; ++tt) {
        uint4 sv[8];
        const uint4* cp = (const uint4*)&c1t[tt][64 * s];
        #pragma unroll
        for (int k = 0; k < 8; ++k) sv[k] = cp[k];
        float d0 = 0.f, d1 = 0.f;
        dot32(d0, wa, sv);
        dot32(d1, wb, sv);
        float D0 = dppadd<0xB1>(d0);     // full-K sum, row 2rq
        float D1 = dppadd<0xB1>(d1);     // full-K sum, row 2rq+1
        float v  = (s ? D1 : D0) + bias;
        gout[(size_t)tt * G4 + 2 * rq + s] = v;
    }
}

// K1c: chunked LAYER-2 recurrence, same (h, 32-col slice) map as k1a.
// Whh2 (64 dw) register-resident; Wih2 contribution read precomputed as one
// aligned float4 (rows 4h..4h+3) with rolling prefetch.  c2 checkpointed
// between chunks; h2(t0-1) reseeded from h2a f32 (bit-identical re-round).
__global__ __launch_bounds__(512)
__attribute__((amdgpu_waves_per_eu(2, 2)))
void k1c_lstm2(
    const float* __restrict__ gi2,
    const unsigned short* __restrict__ wh2p,
    float* __restrict__ h2a, float* __restrict__ c2s, int t0)
{
    __shared__ __align__(16) unsigned short h2h[2][HH];

    const int tid = threadIdx.x;
    const int b   = blockIdx.x;
    const int s   = tid & 3;             // 32-col slice
    const int h   = tid >> 2;            // unit 0..127

    uint4 w2[4][4];                      // 4 rows x 32 cols = 64 dwords
    #pragma unroll
    for (int r = 0; r < 4; ++r) {
        const uint4* p1 = (const uint4*)(wh2p + (size_t)(4 * h + r) * HH + 32 * s);
        #pragma unroll
        for (int k = 0; k < 4; ++k) w2[r][k] = p1[k];
    }

    if (tid < HH) {
        unsigned short hv = 0;
        if (t0 > 0) hv = f16b(h2a[((size_t)(t0 - 1) * BB + b) * HH + tid]);
        h2h[0][tid] = hv;
        h2h[1][tid] = 0;
    }
    float c2reg = (t0 > 0) ? c2s[b * HH + h] : 0.f;   // replicated
    __syncthreads();

    const float* gbase = gi2 + (size_t)b * TCHUNK * G4 + 4 * h;
    float* outp = h2a + (size_t)b * HH + h;

    float4 gc = *(const float4*)gbase;   // tc=0: rows 4h..4h+3 (i,f,g,o)
    for (int ts = 0; ts < TCHUNK; ++ts) {
        const int p = ts & 1, q = p ^ 1;

        float4 gn = make_float4(0.f, 0.f, 0.f, 0.f);
        if (ts + 1 < TCHUNK) gn = *(const float4*)(gbase + (size_t)(ts + 1) * G4);

        uint4 sv[4];
        const uint4* hp = (const uint4*)&h2h[p][32 * s];
        #pragma unroll
        for (int k = 0; k < 4; ++k) sv[k] = hp[k];
        float a0 = dotrow32(w2[0], sv);
        float a1 = dotrow32(w2[1], sv);
        float a2 = dotrow32(w2[2], sv);
        float a3 = dotrow32(w2[3], sv);
        a0 = qsum(a0); a1 = qsum(a1); a2 = qsum(a2); a3 = qsum(a3);

        float gi = a0 + gc.x;
        float gf = a1 + gc.y;
        float gg = a2 + gc.z;
        float go = a3 + gc.w;
        float cn = sigf(gf) * c2reg + sigf(gi) * tanhf_(gg);
        c2reg = cn;
        float hn = sigf(go) * tanhf_(cn);
        if (s == 0) {
            h2h[q][h] = f16b(hn);
            outp[(size_t)(t0 + ts) * (BB * HH)] = hn;
        }
        gc = gn;
        STEP_BARRIER();
    }
    if (s == 0) c2s[b * HH + h] = c2reg;   // checkpoint for next chunk
}

// K2: d_old[t,b] = h2[t,b,:].wt_old ; d_h[t,b] = h2[t,b,:].wt_h  (unchanged)
__global__ __launch_bounds__(256) void k2_dots(
    const float* __restrict__ h2a, const float* __restrict__ w_t,
    float* __restrict__ dold, float* __restrict__ dh)
{
    const int lane = threadIdx.x & 63;
    const int wave = blockIdx.x * (blockDim.x >> 6) + (threadIdx.x >> 6);
    const int nw = gridDim.x * (blockDim.x >> 6);
    const float wh0 = w_t[lane],       wh1 = w_t[64 + lane];
    const float wo0 = w_t[128 + lane], wo1 = w_t[192 + lane];
    for (int row = wave; row < TT * BB; row += nw) {
        const float* p = h2a + (size_t)row * HH;
        float v0 = p[lane], v1 = p[64 + lane];
        float po = v0 * wo0 + v1 * wo1;
        float ph = v0 * wh0 + v1 * wh1;
        #pragma unroll
        for (int off = 32; off; off >>= 1) {
            po += __shfl_xor(po, off);
            ph += __shfl_xor(ph, off);
        }
        if (lane == 0) { dold[row] = po; dh[row] = ph; }
    }
}

// K3: per-t global softmax stats over valid (j,b): m[t], s[t]  (unchanged)
__global__ __launch_bounds__(256) void k3_stats(
    const float* __restrict__ dold, const float* __restrict__ dh,
    float* __restrict__ mt, float* __restrict__ st)
{
    const int t = blockIdx.x;
    const int tid = threadIdx.x;
    const int cnt = (min(t, WW) + 1) * BB;
    const int jstart = max(t - (WW + 1), -1);

    float m = -INFINITY;
    for (int idx = tid; idx < cnt; idx += 256) {
        int jj = idx >> 7, b = idx & 127;
        int j = jstart + jj;
        float sc = dh[t * BB + b] + (j >= 0 ? dold[j * BB + b] : 0.f);
        m = fmaxf(m, sc);
    }
    #pragma unroll
    for (int off = 32; off; off >>= 1) m = fmaxf(m, __shfl_xor(m, off));
    __shared__ float rbuf[4];
    int wv = tid >> 6, ln = tid & 63;
    if (ln == 0) rbuf[wv] = m;
    __syncthreads();
    m = fmaxf(fmaxf(rbuf[0], rbuf[1]), fmaxf(rbuf[2], rbuf[3]));

    float s = 0.f;
    for (int idx = tid; idx < cnt; idx += 256) {
        int jj = idx >> 7, b = idx & 127;
        int j = jstart + jj;
        float sc = dh[t * BB + b] + (j >= 0 ? dold[j * BB + b] : 0.f);
        s += __expf(sc - m);
    }
    #pragma unroll
    for (int off = 32; off; off >>= 1) s += __shfl_xor(s, off);
    __shared__ float sbuf[4];
    if (ln == 0) sbuf[wv] = s;
    __syncthreads();
    if (tid == 0) { mt[t] = m; st[t] = sbuf[0] + sbuf[1] + sbuf[2] + sbuf[3]; }
}

// K45: fused attention + FC. grid (TT/8, BB), block 256.  (unchanged)
__global__ __launch_bounds__(256) void k45_attn_fc(
    const float* __restrict__ h2a,
    const float* __restrict__ dold, const float* __restrict__ dh,
    const float* __restrict__ mt, const float* __restrict__ st,
    const float* __restrict__ fcWT, const float* __restrict__ fcb,
    float* __restrict__ out)
{
    const int t0 = blockIdx.x * 8;
    const int b  = blockIdx.y;
    const int tid = threadIdx.x;

    __shared__ float hbuf[41][HH];     // rows t0-33 .. t0+7
    __shared__ float wjs[8][36];
    __shared__ float ytile[8][HH];

    for (int i = tid; i < 41 * 32; i += 256) {
        int r = i >> 5, q4 = i & 31;
        int t = t0 - 33 + r;
        float4 v = make_float4(0.f, 0.f, 0.f, 0.f);
        if (t >= 0)
            v = *(const float4*)(h2a + (size_t)t * (BB * HH) + (size_t)b * HH + q4 * 4);
        *(float4*)&hbuf[r][q4 * 4] = v;
    }
    for (int i = tid; i < 8 * 33; i += 256) {
        int tt = i / 33, ss = i % 33;
        int t = t0 + tt, j = t - 33 + ss;
        float w = 0.f;
        if (j >= 0)
            w = __expf(dold[j * BB + b] + dh[t * BB + b] - mt[t]) / st[t];
        wjs[tt][ss] = w;
    }
    __syncthreads();

    {
        const int tq = tid >> 5;
        const int hq = (tid & 31) * 4;
        float4 acc = *(const float4*)&hbuf[tq + 33][hq];   // h2[t]
        #pragma unroll 11
        for (int ss = 0; ss < 33; ++ss) {
            float w = wjs[tq][ss];
            float4 hb = *(const float4*)&hbuf[tq + ss][hq];
            acc.x = fmaf(w, hb.x, acc.x);
            acc.y = fmaf(w, hb.y, acc.y);
            acc.z = fmaf(w, hb.z, acc.z);
            acc.w = fmaf(w, hb.w, acc.w);
        }
        *(float4*)&ytile[tq][hq] = acc;
    }
    __syncthreads();

    {
        const int c  = tid & 127;
        const int th = tid >> 7;
        float acc[4];
        const float bias = fcb[c];
        #pragma unroll
        for (int i = 0; i < 4; ++i) acc[i] = bias;
        for (int hh = 0; hh < HH; ++hh) {
            float w = fcWT[hh * CC + c];
            #pragma unroll
            for (int i = 0; i < 4; ++i)
                acc[i] = fmaf(ytile[th * 4 + i][hh], w, acc[i]);
        }
        #pragma unroll
        for (int i = 0; i < 4; ++i) {
            int t = t0 + th * 4 + i;
            out[(size_t)b * (TT * CC) + (size_t)t * CC + c] = acc[i];
        }
    }
}

extern "C" void kernel_launch(void* const* d_in, const int* in_sizes, int n_in,
                              void* d_out, int out_size, void* d_ws, size_t ws_size,
                              hipStream_t stream)
{
    const float* x    = (const float*)d_in[0];
    const float* Wih1 = (const float*)d_in[1];
    const float* Whh1 = (const float*)d_in[2];
    const float* bih1 = (const float*)d_in[3];
    const float* bhh1 = (const float*)d_in[4];
    const float* Wih2 = (const float*)d_in[5];
    const float* Whh2 = (const float*)d_in[6];
    const float* bih2 = (const float*)d_in[7];
    const float* bhh2 = (const float*)d_in[8];
    const float* w_t  = (const float*)d_in[9];
    const float* fcW  = (const float*)d_in[10];
    const float* fcb  = (const float*)d_in[11];
    float* out = (float*)d_out;

    float* ws   = (float*)d_ws;
    float* fcWT = ws + OFF_FCWT;
    unsigned short* w1p  = (unsigned short*)(ws + OFF_W1P);
    unsigned short* wi2p = (unsigned short*)(ws + OFF_WI2P);
    unsigned short* wh2p = (unsigned short*)(ws + OFF_WH2P);
    float* b1pp = ws + OFF_B1P;
    float* wi1p = ws + OFF_WI1P;
    float* b2pp = ws + OFF_B2P;
    float* h2a  = ws + OFF_H2A;
    float* dold = ws + OFF_DOLD;
    float* dh   = ws + OFF_DH;
    float* mt   = ws + OFF_MT;
    float* st   = ws + OFF_ST;
    unsigned short* c1f = (unsigned short*)(ws + OFF_C1F);
    float* c2s  = ws + OFF_C2S;
    float* gi2  = ws + OFF_GI2;

    k0_prep<<<dim3((G4 * HH + 255) / 256), dim3(256), 0, stream>>>(
        Whh1, Wih2, Whh2, fcW, Wih1, bih1, bhh1, bih2, bhh2,
        fcWT, w1p, wi2p, wh2p, b1pp, wi1p, b2pp);

    k1a_lstm1<<<dim3(BB), dim3(512), 0, stream>>>(
        x, b1pp, wi1p, w1p, c1f);

    for (int t0 = 0; t0 < TT; t0 += TCHUNK) {
        k1b_gemm<<<dim3(TCHUNK / 16, BB), dim3(512), 0, stream>>>(
            c1f, wi2p, b2pp, gi2, t0);
        k1c_lstm2<<<dim3(BB), dim3(512), 0, stream>>>(
            gi2, wh2p, h2a, c2s, t0);
    }

    k2_dots<<<dim3(256), dim3(256), 0, stream>>>(h2a, w_t, dold, dh);

    k3_stats<<<dim3(TT), dim3(256), 0, stream>>>(dold, dh, mt, st);

    k45_attn_fc<<<dim3(TT / 8, BB), dim3(256), 0, stream>>>(
        h2a, dold, dh, mt, st, fcWT, fcb, out);
}

// Round 14
// 762.288 us; speedup vs baseline: 1.5204x; 1.1707x over previous
//
#include <hip/hip_runtime.h>
#include <math.h>

#define BB 128
#define TT 512
#define HH 128
#define G4 512      // 4*H
#define CC 128
#define WW 32
#define TCHUNK 128  // time chunk (4 chunks), pipelined across launches

// ---- workspace layout (float slots) ----
#define OFF_FCWT  0                          // 16384
#define OFF_W1P   (OFF_FCWT + CC*HH)         // f16 permuted Whh1: 32768 slots
#define OFF_WI2P  (OFF_W1P  + G4*HH/2)
#define OFF_WH2P  (OFF_WI2P + G4*HH/2)
#define OFF_B1P   (OFF_WH2P + G4*HH/2)       // 512
#define OFF_WI1P  (OFF_B1P + G4)
#define OFF_B2P   (OFF_WI1P + G4)
#define OFF_H2A   (OFF_B2P + G4)             // [T][B][H] fp32
#define OFF_DOLD  (OFF_H2A + TT*BB*HH)
#define OFF_DH    (OFF_DOLD + TT*BB)
#define OFF_MT    (OFF_DH + TT*BB)
#define OFF_ST    (OFF_MT + TT)
#define OFF_C1F   (OFF_ST + TT)              // f16 [t][b][h]: TT*BB*HH/2 slots
#define OFF_C2S   (OFF_C1F + TT*BB*HH/2)     // f32 [b][h] c2 checkpoint
#define OFF_C1S   (OFF_C2S + BB*HH)          // f32 [b][h] c1 checkpoint
#define OFF_H1S   (OFF_C1S + BB*HH)          // f16 [b][h] h1 checkpoint (BB*HH/2)
#define OFF_GI2   (OFF_H1S + BB*HH/2)        // f32 x2 ping-pong: 2*TCHUNK*BB*G4
// top ~= 29.6M floats ~= 118 MB (R9 executed at this size)

typedef _Float16 h2t __attribute__((ext_vector_type(2)));

__device__ __forceinline__ unsigned short f16b(float v) {
    return __builtin_bit_cast(unsigned short, (_Float16)v);
}
__device__ __forceinline__ float dot2f(unsigned int a, unsigned int b, float acc) {
#if defined(__has_builtin) && __has_builtin(__builtin_amdgcn_fdot2)
    return __builtin_amdgcn_fdot2(__builtin_bit_cast(h2t, a),
                                  __builtin_bit_cast(h2t, b), acc, false);
#else
    h2t av = __builtin_bit_cast(h2t, a), bv = __builtin_bit_cast(h2t, b);
    acc = fmaf((float)av.x, (float)bv.x, acc);
    acc = fmaf((float)av.y, (float)bv.y, acc);
    return acc;
#endif
}
__device__ __forceinline__ float rcpf(float x) {
#if defined(__has_builtin) && __has_builtin(__builtin_amdgcn_rcpf)
    return __builtin_amdgcn_rcpf(x);
#else
    return 1.f / x;
#endif
}
__device__ __forceinline__ float sigf(float v) {
    return rcpf(1.f + __expf(-v));
}
__device__ __forceinline__ float tanhf_(float v) {
    return fmaf(2.f, rcpf(1.f + __expf(-2.f * v)), -1.f);
}

// DPP quad_perm helpers (pure VALU, quad-local).
template <int CTRL>
__device__ __forceinline__ float dppadd(float v) {
#if defined(__has_builtin) && __has_builtin(__builtin_amdgcn_update_dpp)
    int m = __builtin_amdgcn_update_dpp(0, __builtin_bit_cast(int, v),
                                        CTRL, 0xf, 0xf, true);
    return v + __builtin_bit_cast(float, m);
#else
    return v + __shfl_xor(v, CTRL == 0xB1 ? 1 : 2);
#endif
}
__device__ __forceinline__ float qsum(float v) {
    v = dppadd<0xB1>(v);
    v = dppadd<0x4E>(v);
    return v;
}

// 32 dot2: one 64-col row-slice (8 uint4 f16 weights) x state (8 uint4)
__device__ __forceinline__ void dot32(float& acc, const uint4* W, const uint4* S) {
    #pragma unroll
    for (int k = 0; k < 8; ++k) {
        acc = dot2f(W[k].x, S[k].x, acc);
        acc = dot2f(W[k].y, S[k].y, acc);
        acc = dot2f(W[k].z, S[k].z, acc);
        acc = dot2f(W[k].w, S[k].w, acc);
    }
}
// 16 dot2: one 32-col row-slice (4 uint4 f16 weights) x state (4 uint4)
__device__ __forceinline__ float dotrow32(const uint4* W, const uint4* S) {
    float acc = 0.f;
    #pragma unroll
    for (int k = 0; k < 4; ++k) {
        acc = dot2f(W[k].x, S[k].x, acc);
        acc = dot2f(W[k].y, S[k].y, acc);
        acc = dot2f(W[k].z, S[k].z, acc);
        acc = dot2f(W[k].w, S[k].w, acc);
    }
    return acc;
}

// LDS-visibility barrier WITHOUT vmcnt drain.
#define STEP_BARRIER() asm volatile("s_waitcnt lgkmcnt(0)\n\ts_barrier" ::: "memory")

// K0: gate-interleaved (r = h*4 + g) f16 weight images + permuted biases +
// fcW transpose.  (unchanged)
__global__ __launch_bounds__(256) void k0_prep(
    const float* __restrict__ Whh1, const float* __restrict__ Wih2,
    const float* __restrict__ Whh2, const float* __restrict__ fcW,
    const float* __restrict__ Wih1,
    const float* __restrict__ bih1, const float* __restrict__ bhh1,
    const float* __restrict__ bih2, const float* __restrict__ bhh2,
    float* __restrict__ fcWT,
    unsigned short* __restrict__ w1p, unsigned short* __restrict__ wi2p,
    unsigned short* __restrict__ wh2p,
    float* __restrict__ b1p, float* __restrict__ wi1p, float* __restrict__ b2p)
{
    int idx = blockIdx.x * blockDim.x + threadIdx.x;
    if (idx < G4 * HH) {
        int r_old = idx >> 7, k = idx & 127;
        int g = r_old >> 7, h = r_old & 127;
        int dst = (h * 4 + g) * HH + k;
        w1p [dst] = f16b(Whh1[idx]);
        wi2p[dst] = f16b(Wih2[idx]);
        wh2p[dst] = f16b(Whh2[idx]);
    }
    if (idx < CC * HH) {
        int c = idx / HH, h = idx % HH;
        fcWT[h * CC + c] = fcW[idx];
    }
    if (idx < G4) {
        int g = idx >> 7, h = idx & 127;
        int rn = h * 4 + g;
        b1p [rn] = bih1[idx] + bhh1[idx];
        wi1p[rn] = Wih1[idx];
        b2p [rn] = bih2[idx] + bhh2[idx];
    }
}

// K1AC: pipelined fused kernel.  Per launch:
//   blocks [0, BB)      (if t0a >= 0): A-role = layer-1 recurrence for chunk
//     [t0a, t0a+TCHUNK)  (R13 k1a math verbatim, chunked with exact-precision
//     checkpoints: c1 in f32 c1s, h1 in f16 h1s = bit-identical to the LDS
//     handoff), then a B-tail: this block computes gi2a[b][0..TCHUNK)[*] =
//     b2 + Wih2 . c1(chunk) for its OWN batch (R11-proven k1b mapping,
//     looped over the chunk's 8 16-row tiles).
//   blocks [BB, 2BB)    (if t0c >= 0): C-role = layer-2 recurrence for chunk
//     [t0c, t0c+TCHUNK)  (R13 k1c verbatim), reading gi2c.
// Launch ladder: [A0B0] -> [A1B1 | C0] -> [A2B2 | C1] -> [A3B3 | C2] -> [C3]
// with gi2 ping-pong (B_i writes one buffer while C_{i-1} reads the other).
// Layer-1 and layer-2 overlap on the 256-CU chip (each role = 128 blocks).
__global__ __launch_bounds__(512)
__attribute__((amdgpu_waves_per_eu(2, 2)))
void k1ac(
    const float* __restrict__ x,
    const float* __restrict__ b1p, const float* __restrict__ wi1p,
    const unsigned short* __restrict__ w1p,
    const unsigned short* __restrict__ wi2p, const float* __restrict__ b2p,
    const unsigned short* __restrict__ wh2p,
    unsigned short* __restrict__ c1f, float* __restrict__ c1s,
    unsigned short* __restrict__ h1s,
    float* __restrict__ h2a, float* __restrict__ c2s,
    float* __restrict__ gi2a, const float* __restrict__ gi2c,
    int t0a, int t0c)
{
    __shared__ __align__(16) unsigned short h1h[2][HH];   // A-role
    __shared__ float xs[TCHUNK];                          // A-role
    __shared__ __align__(16) unsigned short c1t[16][HH];  // A-role B-tail
    __shared__ __align__(16) unsigned short h2h[2][HH];   // C-role

    const int tid = threadIdx.x;
    const bool hasA = (t0a >= 0);

    if (hasA && (int)blockIdx.x < BB) {
        // ================= A-role: layer-1 chunk + B-tail =================
        const int b = blockIdx.x;
        const int s = tid & 3;             // 32-col slice
        const int h = tid >> 2;            // unit 0..127

        uint4 w1[4][4];
        float wi1v[4], b1v[4];
        #pragma unroll
        for (int r = 0; r < 4; ++r) {
            const uint4* p1 = (const uint4*)(w1p + (size_t)(4 * h + r) * HH + 32 * s);
            #pragma unroll
            for (int k = 0; k < 4; ++k) w1[r][k] = p1[k];
            wi1v[r] = wi1p[4 * h + r];
            b1v[r]  = b1p [4 * h + r];
        }

        if (tid < TCHUNK) xs[tid] = x[(size_t)b * TT + t0a + tid];
        float c1reg;
        if (t0a == 0) {
            if (tid < HH) { h1h[0][tid] = 0; }
            c1reg = 0.f;
        } else {
            if (tid < HH) h1h[0][tid] = h1s[b * HH + tid];
            c1reg = c1s[b * HH + h];
        }
        __syncthreads();

        unsigned short* outc = c1f + ((size_t)t0a * BB + b) * HH + h;

        for (int ts = 0; ts < TCHUNK; ++ts) {
            const int p = ts & 1, q = p ^ 1;
            const float xv = xs[ts];

            uint4 sv[4];
            const uint4* hp = (const uint4*)&h1h[p][32 * s];
            #pragma unroll
            for (int k = 0; k < 4; ++k) sv[k] = hp[k];
            float a0 = dotrow32(w1[0], sv);
            float a1 = dotrow32(w1[1], sv);
            float a2 = dotrow32(w1[2], sv);
            float a3 = dotrow32(w1[3], sv);
            a0 = qsum(a0); a1 = qsum(a1); a2 = qsum(a2); a3 = qsum(a3);

            float gi = a0 + fmaf(xv, wi1v[0], b1v[0]);
            float gf = a1 + fmaf(xv, wi1v[1], b1v[1]);
            float gg = a2 + fmaf(xv, wi1v[2], b1v[2]);
            float go = a3 + fmaf(xv, wi1v[3], b1v[3]);
            float cn = sigf(gf) * c1reg + sigf(gi) * tanhf_(gg);
            c1reg = cn;
            float hn = sigf(go) * tanhf_(cn);
            if (s == 0) {
                h1h[q][h] = f16b(hn);
                outc[(size_t)ts * (BB * HH)] = f16b(cn);
                if (ts == TCHUNK - 1) h1s[b * HH + h] = f16b(hn);
            }
            STEP_BARRIER();
        }
        if (s == 0) c1s[b * HH + h] = c1reg;   // exact f32 checkpoint

        // ---- B-tail: gi2a[b][tc][r] = b2[r] + Wih2[r,:].c1[t0a+tc,b,:] ----
        // Wait for this block's own c1f stores, then R11-proven k1b mapping.
        asm volatile("s_waitcnt vmcnt(0)" ::: "memory");
        const int rq = tid >> 1;           // rows 2rq, 2rq+1
        const int sB = tid & 1;            // col half
        uint4 wa[8], wb[8];
        {
            const uint4* pa = (const uint4*)(wi2p + (size_t)(2 * rq) * HH + 64 * sB);
            const uint4* pb = (const uint4*)(wi2p + (size_t)(2 * rq + 1) * HH + 64 * sB);
            #pragma unroll
            for (int k = 0; k < 8; ++k) { wa[k] = pa[k]; wb[k] = pb[k]; }
        }
        const float bias = b2p[2 * rq + sB];
        float* gout = gi2a + (size_t)b * TCHUNK * G4;
        for (int tg = 0; tg < TCHUNK; tg += 16) {
            __syncthreads();
            {
                int row = tid >> 5;        // 0..15
                int col = (tid & 31) * 4;  // halfwords
                *(uint2*)&c1t[row][col] =
                    *(const uint2*)(c1f + ((size_t)(t0a + tg + row) * BB + b) * HH + col);
            }
            __syncthreads();
            #pragma unroll 4
            for (int tt = 0; tt < 16; ++tt) {
                uint4 sv[8];
                const uint4* cp = (const uint4*)&c1t[tt][64 * sB];
                #pragma unroll
                for (int k = 0; k < 8; ++k) sv[k] = cp[k];
                float d0 = 0.f, d1 = 0.f;
                dot32(d0, wa, sv);
                dot32(d1, wb, sv);
                float D0 = dppadd<0xB1>(d0);
                float D1 = dppadd<0xB1>(d1);
                float v  = (sB ? D1 : D0) + bias;
                gout[(size_t)(tg + tt) * G4 + 2 * rq + sB] = v;
            }
        }
    } else {
        // ================= C-role: layer-2 chunk (R13 k1c verbatim) =======
        const int b = blockIdx.x - (hasA ? BB : 0);
        const int s = tid & 3;
        const int h = tid >> 2;
        const int t0 = t0c;

        uint4 w2[4][4];
        #pragma unroll
        for (int r = 0; r < 4; ++r) {
            const uint4* p1 = (const uint4*)(wh2p + (size_t)(4 * h + r) * HH + 32 * s);
            #pragma unroll
            for (int k = 0; k < 4; ++k) w2[r][k] = p1[k];
        }

        if (tid < HH) {
            unsigned short hv = 0;
            if (t0 > 0) hv = f16b(h2a[((size_t)(t0 - 1) * BB + b) * HH + tid]);
            h2h[0][tid] = hv;
            h2h[1][tid] = 0;
        }
        float c2reg = (t0 > 0) ? c2s[b * HH + h] : 0.f;
        __syncthreads();

        const float* gbase = gi2c + (size_t)b * TCHUNK * G4 + 4 * h;
        float* outp = h2a + (size_t)b * HH + h;

        float4 gc = *(const float4*)gbase;
        for (int ts = 0; ts < TCHUNK; ++ts) {
            const int p = ts & 1, q = p ^ 1;

            float4 gn = make_float4(0.f, 0.f, 0.f, 0.f);
            if (ts + 1 < TCHUNK) gn = *(const float4*)(gbase + (size_t)(ts + 1) * G4);

            uint4 sv[4];
            const uint4* hp = (const uint4*)&h2h[p][32 * s];
            #pragma unroll
            for (int k = 0; k < 4; ++k) sv[k] = hp[k];
            float a0 = dotrow32(w2[0], sv);
            float a1 = dotrow32(w2[1], sv);
            float a2 = dotrow32(w2[2], sv);
            float a3 = dotrow32(w2[3], sv);
            a0 = qsum(a0); a1 = qsum(a1); a2 = qsum(a2); a3 = qsum(a3);

            float gi = a0 + gc.x;
            float gf = a1 + gc.y;
            float gg = a2 + gc.z;
            float go = a3 + gc.w;
            float cn = sigf(gf) * c2reg + sigf(gi) * tanhf_(gg);
            c2reg = cn;
            float hn = sigf(go) * tanhf_(cn);
            if (s == 0) {
                h2h[q][h] = f16b(hn);
                outp[(size_t)(t0 + ts) * (BB * HH)] = hn;
            }
            gc = gn;
            STEP_BARRIER();
        }
        if (s == 0) c2s[b * HH + h] = c2reg;
    }
}

// K2: d_old[t,b] = h2[t,b,:].wt_old ; d_h[t,b] = h2[t,b,:].wt_h  (unchanged)
__global__ __launch_bounds__(256) void k2_dots(
    const float* __restrict__ h2a, const float* __restrict__ w_t,
    float* __restrict__ dold, float* __restrict__ dh)
{
    const int lane = threadIdx.x & 63;
    const int wave = blockIdx.x * (blockDim.x >> 6) + (threadIdx.x >> 6);
    const int nw = gridDim.x * (blockDim.x >> 6);
    const float wh0 = w_t[lane],       wh1 = w_t[64 + lane];
    const float wo0 = w_t[128 + lane], wo1 = w_t[192 + lane];
    for (int row = wave; row < TT * BB; row += nw) {
        const float* p = h2a + (size_t)row * HH;
        float v0 = p[lane], v1 = p[64 + lane];
        float po = v0 * wo0 + v1 * wo1;
        float ph = v0 * wh0 + v1 * wh1;
        #pragma unroll
        for (int off = 32; off; off >>= 1) {
            po += __shfl_xor(po, off);
            ph += __shfl_xor(ph, off);
        }
        if (lane == 0) { dold[row] = po; dh[row] = ph; }
    }
}

// K3: per-t global softmax stats over valid (j,b): m[t], s[t]  (unchanged)
__global__ __launch_bounds__(256) void k3_stats(
    const float* __restrict__ dold, const float* __restrict__ dh,
    float* __restrict__ mt, float* __restrict__ st)
{
    const int t = blockIdx.x;
    const int tid = threadIdx.x;
    const int cnt = (min(t, WW) + 1) * BB;
    const int jstart = max(t - (WW + 1), -1);

    float m = -INFINITY;
    for (int idx = tid; idx < cnt; idx += 256) {
        int jj = idx >> 7, b = idx & 127;
        int j = jstart + jj;
        float sc = dh[t * BB + b] + (j >= 0 ? dold[j * BB + b] : 0.f);
        m = fmaxf(m, sc);
    }
    #pragma unroll
    for (int off = 32; off; off >>= 1) m = fmaxf(m, __shfl_xor(m, off));
    __shared__ float rbuf[4];
    int wv = tid >> 6, ln = tid & 63;
    if (ln == 0) rbuf[wv] = m;
    __syncthreads();
    m = fmaxf(fmaxf(rbuf[0], rbuf[1]), fmaxf(rbuf[2], rbuf[3]));

    float s = 0.f;
    for (int idx = tid; idx < cnt; idx += 256) {
        int jj = idx >> 7, b = idx & 127;
        int j = jstart + jj;
        float sc = dh[t * BB + b] + (j >= 0 ? dold[j * BB + b] : 0.f);
        s += __expf(sc - m);
    }
    #pragma unroll
    for (int off = 32; off; off >>= 1) s += __shfl_xor(s, off);
    __shared__ float sbuf[4];
    if (ln == 0) sbuf[wv] = s;
    __syncthreads();
    if (tid == 0) { mt[t] = m; st[t] = sbuf[0] + sbuf[1] + sbuf[2] + sbuf[3]; }
}

// K45: fused attention + FC. grid (TT/8, BB), block 256.  (unchanged)
__global__ __launch_bounds__(256) void k45_attn_fc(
    const float* __restrict__ h2a,
    const float* __restrict__ dold, const float* __restrict__ dh,
    const float* __restrict__ mt, const float* __restrict__ st,
    const float* __restrict__ fcWT, const float* __restrict__ fcb,
    float* __restrict__ out)
{
    const int t0 = blockIdx.x * 8;
    const int b  = blockIdx.y;
    const int tid = threadIdx.x;

    __shared__ float hbuf[41][HH];     // rows t0-33 .. t0+7
    __shared__ float wjs[8][36];
    __shared__ float ytile[8][HH];

    for (int i = tid; i < 41 * 32; i += 256) {
        int r = i >> 5, q4 = i & 31;
        int t = t0 - 33 + r;
        float4 v = make_float4(0.f, 0.f, 0.f, 0.f);
        if (t >= 0)
            v = *(const float4*)(h2a + (size_t)t * (BB * HH) + (size_t)b * HH + q4 * 4);
        *(float4*)&hbuf[r][q4 * 4] = v;
    }
    for (int i = tid; i < 8 * 33; i += 256) {
        int tt = i / 33, ss = i % 33;
        int t = t0 + tt, j = t - 33 + ss;
        float w = 0.f;
        if (j >= 0)
            w = __expf(dold[j * BB + b] + dh[t * BB + b] - mt[t]) / st[t];
        wjs[tt][ss] = w;
    }
    __syncthreads();

    {
        const int tq = tid >> 5;
        const int hq = (tid & 31) * 4;
        float4 acc = *(const float4*)&hbuf[tq + 33][hq];   // h2[t]
        #pragma unroll 11
        for (int ss = 0; ss < 33; ++ss) {
            float w = wjs[tq][ss];
            float4 hb = *(const float4*)&hbuf[tq + ss][hq];
            acc.x = fmaf(w, hb.x, acc.x);
            acc.y = fmaf(w, hb.y, acc.y);
            acc.z = fmaf(w, hb.z, acc.z);
            acc.w = fmaf(w, hb.w, acc.w);
        }
        *(float4*)&ytile[tq][hq] = acc;
    }
    __syncthreads();

    {
        const int c  = tid & 127;
        const int th = tid >> 7;
        float acc[4];
        const float bias = fcb[c];
        #pragma unroll
        for (int i = 0; i < 4; ++i) acc[i] = bias;
        for (int hh = 0; hh < HH; ++hh) {
            float w = fcWT[hh * CC + c];
            #pragma unroll
            for (int i = 0; i < 4; ++i)
                acc[i] = fmaf(ytile[th * 4 + i][hh], w, acc[i]);
        }
        #pragma unroll
        for (int i = 0; i < 4; ++i) {
            int t = t0 + th * 4 + i;
            out[(size_t)b * (TT * CC) + (size_t)t * CC + c] = acc[i];
        }
    }
}

extern "C" void kernel_launch(void* const* d_in, const int* in_sizes, int n_in,
                              void* d_out, int out_size, void* d_ws, size_t ws_size,
                              hipStream_t stream)
{
    const float* x    = (const float*)d_in[0];
    const float* Wih1 = (const float*)d_in[1];
    const float* Whh1 = (const float*)d_in[2];
    const float* bih1 = (const float*)d_in[3];
    const float* bhh1 = (const float*)d_in[4];
    const float* Wih2 = (const float*)d_in[5];
    const float* Whh2 = (const float*)d_in[6];
    const float* bih2 = (const float*)d_in[7];
    const float* bhh2 = (const float*)d_in[8];
    const float* w_t  = (const float*)d_in[9];
    const float* fcW  = (const float*)d_in[10];
    const float* fcb  = (const float*)d_in[11];
    float* out = (float*)d_out;

    float* ws   = (float*)d_ws;
    float* fcWT = ws + OFF_FCWT;
    unsigned short* w1p  = (unsigned short*)(ws + OFF_W1P);
    unsigned short* wi2p = (unsigned short*)(ws + OFF_WI2P);
    unsigned short* wh2p = (unsigned short*)(ws + OFF_WH2P);
    float* b1pp = ws + OFF_B1P;
    float* wi1p = ws + OFF_WI1P;
    float* b2pp = ws + OFF_B2P;
    float* h2a  = ws + OFF_H2A;
    float* dold = ws + OFF_DOLD;
    float* dh   = ws + OFF_DH;
    float* mt   = ws + OFF_MT;
    float* st   = ws + OFF_ST;
    unsigned short* c1f = (unsigned short*)(ws + OFF_C1F);
    float* c2s  = ws + OFF_C2S;
    float* c1s  = ws + OFF_C1S;
    unsigned short* h1s = (unsigned short*)(ws + OFF_H1S);
    float* gi2b0 = ws + OFF_GI2;
    float* gi2b1 = gi2b0 + (size_t)TCHUNK * BB * G4;

    k0_prep<<<dim3((G4 * HH + 255) / 256), dim3(256), 0, stream>>>(
        Whh1, Wih2, Whh2, fcW, Wih1, bih1, bhh1, bih2, bhh2,
        fcWT, w1p, wi2p, wh2p, b1pp, wi1p, b2pp);

    // Pipeline: [A0B0] -> [A1B1|C0] -> [A2B2|C1] -> [A3B3|C2] -> [C3]
    float* bufs[2] = { gi2b0, gi2b1 };
    k1ac<<<dim3(BB), dim3(512), 0, stream>>>(
        x, b1pp, wi1p, w1p, wi2p, b2pp, wh2p,
        c1f, c1s, h1s, h2a, c2s, bufs[0], bufs[1], 0, -1);
    for (int i = 1; i < 4; ++i) {
        k1ac<<<dim3(2 * BB), dim3(512), 0, stream>>>(
            x, b1pp, wi1p, w1p, wi2p, b2pp, wh2p,
            c1f, c1s, h1s, h2a, c2s,
            bufs[i & 1], bufs[(i - 1) & 1],
            i * TCHUNK, (i - 1) * TCHUNK);
    }
    k1ac<<<dim3(BB), dim3(512), 0, stream>>>(
        x, b1pp, wi1p, w1p, wi2p, b2pp, wh2p,
        c1f, c1s, h1s, h2a, c2s, bufs[0], bufs[1], -1, 3 * TCHUNK);

    k2_dots<<<dim3(256), dim3(256), 0, stream>>>(h2a, w_t, dold, dh);

    k3_stats<<<dim3(TT), dim3(256), 0, stream>>>(dold, dh, mt, st);

    k45_attn_fc<<<dim3(TT / 8, BB), dim3(256), 0, stream>>>(
        h2a, dold, dh, mt, st, fcWT, fcb, out);
}